// Round 1
// baseline (1767.986 us; speedup 1.0000x reference)
//
#include <hip/hip_runtime.h>

#define HIDDEN 128
#define N_REL 8

__device__ inline float dot4f(float4 a, float4 b) {
  return a.x*b.x + a.y*b.y + a.z*b.z + a.w*b.w;
}

// ---------------- utility: zero a float4 range ----------------
__global__ void zero_f4(float4* __restrict__ p, int n4) {
  int i = blockIdx.x * blockDim.x + threadIdx.x;
  int stride = gridDim.x * blockDim.x;
  for (; i < n4; i += stride) p[i] = make_float4(0.f, 0.f, 0.f, 0.f);
}

// ---------------- histogram of edge types + in-degree ----------------
__global__ void hist_deg(const int* __restrict__ et, const int* __restrict__ ei,
                         int E, int* __restrict__ deg, int* __restrict__ counts) {
  __shared__ int lh[N_REL];
  if (threadIdx.x < N_REL) lh[threadIdx.x] = 0;
  __syncthreads();
  int i = blockIdx.x * blockDim.x + threadIdx.x;
  int stride = gridDim.x * blockDim.x;
  for (int e = i; e < E; e += stride) {
    atomicAdd(&lh[et[e]], 1);
    atomicAdd(&deg[ei[E + e]], 1);   // dst row of edge_index
  }
  __syncthreads();
  if (threadIdx.x < N_REL) atomicAdd(&counts[threadIdx.x], lh[threadIdx.x]);
}

// ---------------- exclusive prefix over 8 counts -> cursor ----------------
__global__ void prefix8(const int* __restrict__ counts, int* __restrict__ cursor) {
  int s = 0;
  for (int r = 0; r < N_REL; ++r) { cursor[r] = s; s += counts[r]; }
}

// ---------------- bucket edges by relation (wave-aggregated atomics) -------
__global__ void scatter_perm(const int* __restrict__ et, int E,
                             int* __restrict__ cursor, int* __restrict__ perm) {
  int i = blockIdx.x * blockDim.x + threadIdx.x;
  int stride = gridDim.x * blockDim.x;
  int lane = threadIdx.x & 63;
  for (int e = i; e < E; e += stride) {
    int r = et[e];
    #pragma unroll
    for (int rr = 0; rr < N_REL; ++rr) {
      unsigned long long m = __ballot(r == rr);
      if (m == 0ull) continue;
      int lsb = __ffsll((long long)m) - 1;
      int posb = 0;
      if (lane == lsb) posb = atomicAdd(&cursor[rr], __popcll(m));
      posb = __shfl(posb, lsb);
      if (r == rr) {
        int off = __popcll(m & ((1ull << lane) - 1ull));
        perm[posb + off] = e;
      }
    }
  }
}

// ---------------- message GEMM + atomic scatter-add ----------------
// 64 edges per block, 256 threads. thread t: jg = t&31 (4 output cols),
// eg = t>>5 (8 edges). W rows read from global (L2-resident, in-wave dedup).
__global__ __launch_bounds__(256) void msg_kernel(
    const float* __restrict__ ns, const int* __restrict__ ei,
    const int* __restrict__ et, const float* __restrict__ Wrel,
    const int* __restrict__ perm, float* __restrict__ agg, int E)
{
  __shared__ float Xs[64][HIDDEN];
  __shared__ int s_src[64], s_dst[64], s_typ[64];
  int t = threadIdx.x;
  int base = blockIdx.x * 64;
  int cnt = min(64, E - base);

  if (t < 64) {
    int typ = 64, src = 0, dst = 0;   // typ=64: matches no relation, safe shift
    if (t < cnt) {
      int eid = perm[base + t];
      src = ei[eid]; dst = ei[E + eid]; typ = et[eid];
    }
    s_src[t] = src; s_dst[t] = dst; s_typ[t] = typ;
  }
  __syncthreads();

  // gather xs rows (coalesced float4 within each 512B row)
  for (int c = t; c < cnt * 32; c += 256) {
    int e = c >> 5, k4 = c & 31;
    const float4* p = (const float4*)(ns + (size_t)s_src[e] * HIDDEN);
    ((float4*)Xs[e])[k4] = p[k4];
  }

  // which relations are present in this block (bucketed: almost always 1)
  unsigned pmask = 0;
  for (int i2 = 0; i2 < cnt; ++i2) {
    int ty = s_typ[i2];
    if (ty < N_REL) pmask |= 1u << ty;
  }
  __syncthreads();

  int jg = t & 31;   // output cols jg*4 .. jg*4+3
  int eg = t >> 5;   // edges eg*8 .. eg*8+7

  int myt[8];
  #pragma unroll
  for (int e = 0; e < 8; ++e) myt[e] = s_typ[eg * 8 + e];

  float acc[8][4];
  #pragma unroll
  for (int e = 0; e < 8; ++e)
    #pragma unroll
    for (int u = 0; u < 4; ++u) acc[e][u] = 0.f;

  for (int r = 0; r < N_REL; ++r) {
    if (!((pmask >> r) & 1u)) continue;
    const float* Wr = Wrel + (size_t)r * HIDDEN * HIDDEN + (size_t)jg * 4 * HIDDEN;
    for (int kc = 0; kc < HIDDEN; kc += 8) {
      float4 wa[4], wb[4];
      #pragma unroll
      for (int u = 0; u < 4; ++u) {
        wa[u] = *(const float4*)(Wr + u * HIDDEN + kc);
        wb[u] = *(const float4*)(Wr + u * HIDDEN + kc + 4);
      }
      #pragma unroll
      for (int e = 0; e < 8; ++e) {
        if (myt[e] != r) continue;
        float4 xa = ((const float4*)Xs[eg * 8 + e])[kc >> 2];
        float4 xb = ((const float4*)Xs[eg * 8 + e])[(kc >> 2) + 1];
        #pragma unroll
        for (int u = 0; u < 4; ++u)
          acc[e][u] += dot4f(xa, wa[u]) + dot4f(xb, wb[u]);
      }
    }
  }

  // scatter-add into agg (= d_out)
  #pragma unroll
  for (int e = 0; e < 8; ++e) {
    int idx = eg * 8 + e;
    if (idx < cnt) {
      float* d = agg + (size_t)s_dst[idx] * HIDDEN + jg * 4;
      #pragma unroll
      for (int u = 0; u < 4; ++u) unsafeAtomicAdd(d + u, acc[e][u]);
    }
  }
}

// ---------------- self transform + bias + mean-agg + relu (in place) -------
__global__ __launch_bounds__(256) void self_kernel(
    const float* __restrict__ ns, const float* __restrict__ Ws,
    const float* __restrict__ b, const int* __restrict__ deg,
    float* __restrict__ out, int N)
{
  __shared__ float Xs[64][HIDDEN];
  int t = threadIdx.x;
  int base = blockIdx.x * 64;
  int cnt = min(64, N - base);

  for (int c = t; c < cnt * 32; c += 256) {
    int e = c >> 5, k4 = c & 31;
    ((float4*)Xs[e])[k4] = ((const float4*)(ns + (size_t)(base + e) * HIDDEN))[k4];
  }
  __syncthreads();

  int jg = t & 31;
  int eg = t >> 5;

  float acc[8][4];
  #pragma unroll
  for (int e = 0; e < 8; ++e)
    #pragma unroll
    for (int u = 0; u < 4; ++u) acc[e][u] = 0.f;

  const float* Wp = Ws + (size_t)jg * 4 * HIDDEN;
  for (int kc = 0; kc < HIDDEN; kc += 8) {
    float4 wa[4], wb[4];
    #pragma unroll
    for (int u = 0; u < 4; ++u) {
      wa[u] = *(const float4*)(Wp + u * HIDDEN + kc);
      wb[u] = *(const float4*)(Wp + u * HIDDEN + kc + 4);
    }
    #pragma unroll
    for (int e = 0; e < 8; ++e) {
      float4 xa = ((const float4*)Xs[eg * 8 + e])[kc >> 2];
      float4 xb = ((const float4*)Xs[eg * 8 + e])[(kc >> 2) + 1];
      #pragma unroll
      for (int u = 0; u < 4; ++u)
        acc[e][u] += dot4f(xa, wa[u]) + dot4f(xb, wb[u]);
    }
  }

  float bj[4];
  *(float4*)bj = *(const float4*)(b + jg * 4);

  #pragma unroll
  for (int e = 0; e < 8; ++e) {
    int n = base + eg * 8 + e;
    if (eg * 8 + e < cnt) {
      float inv = 1.0f / (float)max(deg[n], 1);
      float* o = out + (size_t)n * HIDDEN + jg * 4;
      #pragma unroll
      for (int u = 0; u < 4; ++u) {
        float v = acc[e][u] + bj[u] + o[u] * inv;
        o[u] = fmaxf(v, 0.f);
      }
    }
  }
}

extern "C" void kernel_launch(void* const* d_in, const int* in_sizes, int n_in,
                              void* d_out, int out_size, void* d_ws, size_t ws_size,
                              hipStream_t stream) {
  const float* node_states = (const float*)d_in[0];
  const int*   edge_index  = (const int*)d_in[1];   // [2, E]
  const int*   edge_type   = (const int*)d_in[2];   // [E]
  const float* W_self      = (const float*)d_in[3];
  const float* b_self      = (const float*)d_in[4];
  const float* W_rel       = (const float*)d_in[5];
  float* out = (float*)d_out;

  const int E = in_sizes[2];
  const int N = in_sizes[0] / HIDDEN;

  // workspace layout (ints): deg[N] | counts[8] | cursor[8] | perm[E]
  int* deg    = (int*)d_ws;
  int* counts = deg + N;
  int* cursor = counts + N_REL;
  int* perm   = cursor + N_REL;

  // zero d_out (agg accumulator) and deg/counts/cursor
  int n4_out = (N * HIDDEN) / 4;
  zero_f4<<<2048, 256, 0, stream>>>((float4*)out, n4_out);
  int n4_misc = (N + N_REL + N_REL + 3) / 4;
  zero_f4<<<64, 256, 0, stream>>>((float4*)deg, n4_misc);

  hist_deg<<<1024, 256, 0, stream>>>(edge_type, edge_index, E, deg, counts);
  prefix8<<<1, 1, 0, stream>>>(counts, cursor);
  scatter_perm<<<1024, 256, 0, stream>>>(edge_type, E, cursor, perm);

  int msg_blocks = (E + 63) / 64;
  msg_kernel<<<msg_blocks, 256, 0, stream>>>(node_states, edge_index, edge_type,
                                             W_rel, perm, out, E);

  int self_blocks = (N + 63) / 64;
  self_kernel<<<self_blocks, 256, 0, stream>>>(node_states, W_self, b_self,
                                               deg, out, N);
}

// Round 2
// 650.649 us; speedup vs baseline: 2.7173x; 2.7173x over previous
//
#include <hip/hip_runtime.h>

#define HIDDEN 128
#define N_REL 8

__device__ inline float dot4f(float4 a, float4 b) {
  return a.x*b.x + a.y*b.y + a.z*b.z + a.w*b.w;
}

// ---------------- utility: zero a float4 range ----------------
__global__ void zero_f4(float4* __restrict__ p, int n4) {
  int i = blockIdx.x * blockDim.x + threadIdx.x;
  int stride = gridDim.x * blockDim.x;
  for (; i < n4; i += stride) p[i] = make_float4(0.f, 0.f, 0.f, 0.f);
}

__global__ void zero_i(int* __restrict__ p, int n) {
  int i = blockIdx.x * blockDim.x + threadIdx.x;
  int stride = gridDim.x * blockDim.x;
  for (; i < n; i += stride) p[i] = 0;
}

// =====================================================================
// NEW PATH: counting-sort by dst -> per-(node,rel) sums T -> fused GEMM
// =====================================================================

// in-degree histogram over dst
__global__ void hist_dst(const int* __restrict__ ei, int E, int* __restrict__ deg) {
  int i = blockIdx.x * blockDim.x + threadIdx.x;
  int stride = gridDim.x * blockDim.x;
  for (int e = i; e < E; e += stride) atomicAdd(&deg[ei[E + e]], 1);
}

// hierarchical exclusive scan over N1 = N+1 elements (deg extended with 0)
__global__ void scan_pass1(const int* __restrict__ deg, int N, int N1,
                           int* __restrict__ rs, int* __restrict__ bsum) {
  __shared__ int sh[256];
  int tid = threadIdx.x;
  int i = blockIdx.x * 256 + tid;
  int v = (i < N) ? deg[i] : 0;
  sh[tid] = v;
  __syncthreads();
  for (int off = 1; off < 256; off <<= 1) {
    int x = (tid >= off) ? sh[tid - off] : 0;
    __syncthreads();
    sh[tid] += x;
    __syncthreads();
  }
  if (i < N1) rs[i] = sh[tid] - v;           // exclusive
  if (tid == 255) bsum[blockIdx.x] = sh[255];
}

__global__ void scan_pass2(int* __restrict__ bsum, int nb) {
  __shared__ int sh[256];
  int tid = threadIdx.x;
  int v = (tid < nb) ? bsum[tid] : 0;
  sh[tid] = v;
  __syncthreads();
  for (int off = 1; off < 256; off <<= 1) {
    int x = (tid >= off) ? sh[tid - off] : 0;
    __syncthreads();
    sh[tid] += x;
    __syncthreads();
  }
  if (tid < nb) bsum[tid] = sh[tid] - v;     // exclusive
}

__global__ void scan_pass3(int* __restrict__ rs, const int* __restrict__ bsum,
                           int* __restrict__ cursor, int N, int N1) {
  int i = blockIdx.x * 256 + threadIdx.x;
  if (i < N1) {
    int v = rs[i] + bsum[blockIdx.x];
    rs[i] = v;
    if (i < N) cursor[i] = v;
  }
}

// scatter edges into dst-sorted order; pack src | (type<<24)
__global__ void scatter_sorted(const int* __restrict__ ei, const int* __restrict__ et,
                               int E, int* __restrict__ cursor, int* __restrict__ sorted) {
  int i = blockIdx.x * blockDim.x + threadIdx.x;
  int stride = gridDim.x * blockDim.x;
  for (int e = i; e < E; e += stride) {
    int d = ei[E + e];
    int pos = atomicAdd(&cursor[d], 1);
    sorted[pos] = ei[e] | (et[e] << 24);
  }
}

// one wave per node: T[v][r][:] = (1/max(deg,1)) * sum of x_src over edges of type r
__global__ __launch_bounds__(256) void gather_T(
    const float* __restrict__ ns, const int* __restrict__ sorted,
    const int* __restrict__ rs, float* __restrict__ T, int N)
{
  int wid = (int)((blockIdx.x * (unsigned)blockDim.x + threadIdx.x) >> 6);
  int lane = threadIdx.x & 63;
  if (wid >= N) return;
  int s0 = rs[wid], s1 = rs[wid + 1];

  float2 acc[N_REL];
  #pragma unroll
  for (int r = 0; r < N_REL; ++r) { acc[r].x = 0.f; acc[r].y = 0.f; }

  for (int eb = s0; eb < s1; eb += 64) {
    int m = min(64, s1 - eb);
    int pk = (lane < m) ? sorted[eb + lane] : 0;
    for (int j = 0; j < m; ++j) {
      int pkj = __shfl(pk, j);
      int src = pkj & 0x00FFFFFF;
      int r = (pkj >> 24) & 7;
      float2 x = *(const float2*)(ns + (size_t)src * HIDDEN + lane * 2);
      #pragma unroll
      for (int rr = 0; rr < N_REL; ++rr)
        if (r == rr) { acc[rr].x += x.x; acc[rr].y += x.y; }
    }
  }

  float inv = (s1 > s0) ? 1.0f / (float)(s1 - s0) : 0.0f;
  float2* Tp = (float2*)(T + (size_t)wid * (N_REL * HIDDEN));
  #pragma unroll
  for (int r = 0; r < N_REL; ++r) {
    float2 o; o.x = acc[r].x * inv; o.y = acc[r].y * inv;
    Tp[r * 64 + lane] = o;
  }
}

// fused: out = relu(x @ Ws^T + b + sum_r T_r @ Wrel[r]^T)
// 64 rows/block, 256 threads; K processed in 9 chunks of 128.
__global__ __launch_bounds__(256) void out_kernel(
    const float* __restrict__ ns, const float* __restrict__ T,
    const float* __restrict__ Ws, const float* __restrict__ Wrel,
    const float* __restrict__ b, float* __restrict__ out, int N)
{
  __shared__ float Xs[64][HIDDEN];
  int t = threadIdx.x;
  int base = blockIdx.x * 64;
  int cnt = min(64, N - base);
  int jg = t & 31;
  int eg = t >> 5;

  float acc[8][4];
  #pragma unroll
  for (int e = 0; e < 8; ++e)
    #pragma unroll
    for (int u = 0; u < 4; ++u) acc[e][u] = 0.f;

  for (int c = 0; c < 9; ++c) {
    for (int q = t; q < cnt * 32; q += 256) {
      int e = q >> 5, k4 = q & 31;
      const float4* p = (c == 0)
          ? (const float4*)(ns + (size_t)(base + e) * HIDDEN)
          : (const float4*)(T + (size_t)(base + e) * (N_REL * HIDDEN) + (c - 1) * HIDDEN);
      ((float4*)Xs[e])[k4] = p[k4];
    }
    __syncthreads();

    const float* Wp = ((c == 0) ? Ws : (Wrel + (size_t)(c - 1) * HIDDEN * HIDDEN))
                      + (size_t)jg * 4 * HIDDEN;
    for (int kc = 0; kc < HIDDEN; kc += 8) {
      float4 wa[4], wb[4];
      #pragma unroll
      for (int u = 0; u < 4; ++u) {
        wa[u] = *(const float4*)(Wp + u * HIDDEN + kc);
        wb[u] = *(const float4*)(Wp + u * HIDDEN + kc + 4);
      }
      #pragma unroll
      for (int e = 0; e < 8; ++e) {
        float4 xa = ((const float4*)Xs[eg * 8 + e])[kc >> 2];
        float4 xb = ((const float4*)Xs[eg * 8 + e])[(kc >> 2) + 1];
        #pragma unroll
        for (int u = 0; u < 4; ++u)
          acc[e][u] += dot4f(xa, wa[u]) + dot4f(xb, wb[u]);
      }
    }
    __syncthreads();
  }

  float bj[4];
  *(float4*)bj = *(const float4*)(b + jg * 4);

  #pragma unroll
  for (int e = 0; e < 8; ++e) {
    int row = eg * 8 + e;
    if (row < cnt) {
      float4 o;
      o.x = fmaxf(acc[e][0] + bj[0], 0.f);
      o.y = fmaxf(acc[e][1] + bj[1], 0.f);
      o.z = fmaxf(acc[e][2] + bj[2], 0.f);
      o.w = fmaxf(acc[e][3] + bj[3], 0.f);
      *(float4*)(out + (size_t)(base + row) * HIDDEN + jg * 4) = o;
    }
  }
}

// =====================================================================
// FALLBACK PATH (round-1): relation-bucketed msg GEMM + atomic scatter
// =====================================================================

__global__ void hist_deg(const int* __restrict__ et, const int* __restrict__ ei,
                         int E, int* __restrict__ deg, int* __restrict__ counts) {
  __shared__ int lh[N_REL];
  if (threadIdx.x < N_REL) lh[threadIdx.x] = 0;
  __syncthreads();
  int i = blockIdx.x * blockDim.x + threadIdx.x;
  int stride = gridDim.x * blockDim.x;
  for (int e = i; e < E; e += stride) {
    atomicAdd(&lh[et[e]], 1);
    atomicAdd(&deg[ei[E + e]], 1);
  }
  __syncthreads();
  if (threadIdx.x < N_REL) atomicAdd(&counts[threadIdx.x], lh[threadIdx.x]);
}

__global__ void prefix8(const int* __restrict__ counts, int* __restrict__ cursor) {
  int s = 0;
  for (int r = 0; r < N_REL; ++r) { cursor[r] = s; s += counts[r]; }
}

__global__ void scatter_perm(const int* __restrict__ et, int E,
                             int* __restrict__ cursor, int* __restrict__ perm) {
  int i = blockIdx.x * blockDim.x + threadIdx.x;
  int stride = gridDim.x * blockDim.x;
  int lane = threadIdx.x & 63;
  for (int e = i; e < E; e += stride) {
    int r = et[e];
    #pragma unroll
    for (int rr = 0; rr < N_REL; ++rr) {
      unsigned long long m = __ballot(r == rr);
      if (m == 0ull) continue;
      int lsb = __ffsll((long long)m) - 1;
      int posb = 0;
      if (lane == lsb) posb = atomicAdd(&cursor[rr], __popcll(m));
      posb = __shfl(posb, lsb);
      if (r == rr) {
        int off = __popcll(m & ((1ull << lane) - 1ull));
        perm[posb + off] = e;
      }
    }
  }
}

__global__ __launch_bounds__(256) void msg_kernel(
    const float* __restrict__ ns, const int* __restrict__ ei,
    const int* __restrict__ et, const float* __restrict__ Wrel,
    const int* __restrict__ perm, float* __restrict__ agg, int E)
{
  __shared__ float Xs[64][HIDDEN];
  __shared__ int s_src[64], s_dst[64], s_typ[64];
  int t = threadIdx.x;
  int base = blockIdx.x * 64;
  int cnt = min(64, E - base);

  if (t < 64) {
    int typ = 64, src = 0, dst = 0;
    if (t < cnt) {
      int eid = perm[base + t];
      src = ei[eid]; dst = ei[E + eid]; typ = et[eid];
    }
    s_src[t] = src; s_dst[t] = dst; s_typ[t] = typ;
  }
  __syncthreads();

  for (int c = t; c < cnt * 32; c += 256) {
    int e = c >> 5, k4 = c & 31;
    const float4* p = (const float4*)(ns + (size_t)s_src[e] * HIDDEN);
    ((float4*)Xs[e])[k4] = p[k4];
  }

  unsigned pmask = 0;
  for (int i2 = 0; i2 < cnt; ++i2) {
    int ty = s_typ[i2];
    if (ty < N_REL) pmask |= 1u << ty;
  }
  __syncthreads();

  int jg = t & 31;
  int eg = t >> 5;

  int myt[8];
  #pragma unroll
  for (int e = 0; e < 8; ++e) myt[e] = s_typ[eg * 8 + e];

  float acc[8][4];
  #pragma unroll
  for (int e = 0; e < 8; ++e)
    #pragma unroll
    for (int u = 0; u < 4; ++u) acc[e][u] = 0.f;

  for (int r = 0; r < N_REL; ++r) {
    if (!((pmask >> r) & 1u)) continue;
    const float* Wr = Wrel + (size_t)r * HIDDEN * HIDDEN + (size_t)jg * 4 * HIDDEN;
    for (int kc = 0; kc < HIDDEN; kc += 8) {
      float4 wa[4], wb[4];
      #pragma unroll
      for (int u = 0; u < 4; ++u) {
        wa[u] = *(const float4*)(Wr + u * HIDDEN + kc);
        wb[u] = *(const float4*)(Wr + u * HIDDEN + kc + 4);
      }
      #pragma unroll
      for (int e = 0; e < 8; ++e) {
        if (myt[e] != r) continue;
        float4 xa = ((const float4*)Xs[eg * 8 + e])[kc >> 2];
        float4 xb = ((const float4*)Xs[eg * 8 + e])[(kc >> 2) + 1];
        #pragma unroll
        for (int u = 0; u < 4; ++u)
          acc[e][u] += dot4f(xa, wa[u]) + dot4f(xb, wb[u]);
      }
    }
  }

  #pragma unroll
  for (int e = 0; e < 8; ++e) {
    int idx = eg * 8 + e;
    if (idx < cnt) {
      float* d = agg + (size_t)s_dst[idx] * HIDDEN + jg * 4;
      #pragma unroll
      for (int u = 0; u < 4; ++u) unsafeAtomicAdd(d + u, acc[e][u]);
    }
  }
}

__global__ __launch_bounds__(256) void self_kernel(
    const float* __restrict__ ns, const float* __restrict__ Ws,
    const float* __restrict__ b, const int* __restrict__ deg,
    float* __restrict__ out, int N)
{
  __shared__ float Xs[64][HIDDEN];
  int t = threadIdx.x;
  int base = blockIdx.x * 64;
  int cnt = min(64, N - base);

  for (int c = t; c < cnt * 32; c += 256) {
    int e = c >> 5, k4 = c & 31;
    ((float4*)Xs[e])[k4] = ((const float4*)(ns + (size_t)(base + e) * HIDDEN))[k4];
  }
  __syncthreads();

  int jg = t & 31;
  int eg = t >> 5;

  float acc[8][4];
  #pragma unroll
  for (int e = 0; e < 8; ++e)
    #pragma unroll
    for (int u = 0; u < 4; ++u) acc[e][u] = 0.f;

  const float* Wp = Ws + (size_t)jg * 4 * HIDDEN;
  for (int kc = 0; kc < HIDDEN; kc += 8) {
    float4 wa[4], wb[4];
    #pragma unroll
    for (int u = 0; u < 4; ++u) {
      wa[u] = *(const float4*)(Wp + u * HIDDEN + kc);
      wb[u] = *(const float4*)(Wp + u * HIDDEN + kc + 4);
    }
    #pragma unroll
    for (int e = 0; e < 8; ++e) {
      float4 xa = ((const float4*)Xs[eg * 8 + e])[kc >> 2];
      float4 xb = ((const float4*)Xs[eg * 8 + e])[(kc >> 2) + 1];
      #pragma unroll
      for (int u = 0; u < 4; ++u)
        acc[e][u] += dot4f(xa, wa[u]) + dot4f(xb, wb[u]);
    }
  }

  float bj[4];
  *(float4*)bj = *(const float4*)(b + jg * 4);

  #pragma unroll
  for (int e = 0; e < 8; ++e) {
    int n = base + eg * 8 + e;
    if (eg * 8 + e < cnt) {
      float inv = 1.0f / (float)max(deg[n], 1);
      float* o = out + (size_t)n * HIDDEN + jg * 4;
      #pragma unroll
      for (int u = 0; u < 4; ++u) {
        float v = acc[e][u] + bj[u] + o[u] * inv;
        o[u] = fmaxf(v, 0.f);
      }
    }
  }
}

// =====================================================================

extern "C" void kernel_launch(void* const* d_in, const int* in_sizes, int n_in,
                              void* d_out, int out_size, void* d_ws, size_t ws_size,
                              hipStream_t stream) {
  const float* node_states = (const float*)d_in[0];
  const int*   edge_index  = (const int*)d_in[1];   // [2, E]
  const int*   edge_type   = (const int*)d_in[2];   // [E]
  const float* W_self      = (const float*)d_in[3];
  const float* b_self      = (const float*)d_in[4];
  const float* W_rel       = (const float*)d_in[5];
  float* out = (float*)d_out;

  const int E = in_sizes[2];
  const int N = in_sizes[0] / HIDDEN;
  const int N1 = N + 1;
  const int NB = (N1 + 255) / 256;

  // new-path workspace layout
  size_t needT = (size_t)N * N_REL * HIDDEN;                        // floats
  size_t need_bytes = (needT + (size_t)N + (size_t)N1 + (size_t)N + 256 + (size_t)E) * 4;

  if (ws_size >= need_bytes && NB <= 256 && N <= (1 << 24)) {
    float* T   = (float*)d_ws;                   // [N][8][128]
    int* deg    = (int*)(T + needT);             // [N]
    int* rs     = deg + N;                       // [N+1]
    int* cursor = rs + N1;                       // [N]
    int* bsum   = cursor + N;                    // [256]
    int* sorted = bsum + 256;                    // [E]

    zero_i<<<64, 256, 0, stream>>>(deg, N);
    hist_dst<<<1024, 256, 0, stream>>>(edge_index, E, deg);
    scan_pass1<<<NB, 256, 0, stream>>>(deg, N, N1, rs, bsum);
    scan_pass2<<<1, 256, 0, stream>>>(bsum, NB);
    scan_pass3<<<NB, 256, 0, stream>>>(rs, bsum, cursor, N, N1);
    scatter_sorted<<<1024, 256, 0, stream>>>(edge_index, edge_type, E, cursor, sorted);
    gather_T<<<(N + 3) / 4, 256, 0, stream>>>(node_states, sorted, rs, T, N);
    out_kernel<<<(N + 63) / 64, 256, 0, stream>>>(node_states, T, W_self, W_rel,
                                                  b_self, out, N);
  } else {
    // fallback: round-1 path
    int* deg    = (int*)d_ws;
    int* counts = deg + N;
    int* cursor = counts + N_REL;
    int* perm   = cursor + N_REL;

    int n4_out = (N * HIDDEN) / 4;
    zero_f4<<<2048, 256, 0, stream>>>((float4*)out, n4_out);
    int n4_misc = (N + N_REL + N_REL + 3) / 4;
    zero_f4<<<64, 256, 0, stream>>>((float4*)deg, n4_misc);

    hist_deg<<<1024, 256, 0, stream>>>(edge_type, edge_index, E, deg, counts);
    prefix8<<<1, 1, 0, stream>>>(counts, cursor);
    scatter_perm<<<1024, 256, 0, stream>>>(edge_type, E, cursor, perm);

    int msg_blocks = (E + 63) / 64;
    msg_kernel<<<msg_blocks, 256, 0, stream>>>(node_states, edge_index, edge_type,
                                               W_rel, perm, out, E);
    int self_blocks = (N + 63) / 64;
    self_kernel<<<self_blocks, 256, 0, stream>>>(node_states, W_self, b_self,
                                                 deg, out, N);
  }
}

// Round 5
// 273.618 us; speedup vs baseline: 6.4615x; 2.3779x over previous
//
#include <hip/hip_runtime.h>

#define HIDDEN 128
#define N_REL 8
#define KBIG 1152   // (1 + N_REL) * HIDDEN

typedef short short8 __attribute__((ext_vector_type(8)));
typedef float f32x4 __attribute__((ext_vector_type(4)));

__device__ inline float dot4f(float4 a, float4 b) {
  return a.x*b.x + a.y*b.y + a.z*b.z + a.w*b.w;
}

__device__ inline unsigned short f32_to_bf16(float f) {
  unsigned u = __float_as_uint(f);
  unsigned r = (u + 0x7FFFu + ((u >> 16) & 1u)) >> 16;   // round-to-nearest-even
  return (unsigned short)r;
}

// ---------------- utilities ----------------
__global__ void zero_i(int* __restrict__ p, int n) {
  int i = blockIdx.x * blockDim.x + threadIdx.x;
  int stride = gridDim.x * blockDim.x;
  for (; i < n; i += stride) p[i] = 0;
}

// ---------------- shared preprocessing: counting-sort by dst ----------------
__global__ void hist_dst(const int* __restrict__ ei, int E, int* __restrict__ deg) {
  int i = blockIdx.x * blockDim.x + threadIdx.x;
  int stride = gridDim.x * blockDim.x;
  for (int e = i; e < E; e += stride) atomicAdd(&deg[ei[E + e]], 1);
}

__global__ void scan_pass1(const int* __restrict__ deg, int N, int N1,
                           int* __restrict__ rs, int* __restrict__ bsum) {
  __shared__ int sh[256];
  int tid = threadIdx.x;
  int i = blockIdx.x * 256 + tid;
  int v = (i < N) ? deg[i] : 0;
  sh[tid] = v;
  __syncthreads();
  for (int off = 1; off < 256; off <<= 1) {
    int x = (tid >= off) ? sh[tid - off] : 0;
    __syncthreads();
    sh[tid] += x;
    __syncthreads();
  }
  if (i < N1) rs[i] = sh[tid] - v;
  if (tid == 255) bsum[blockIdx.x] = sh[255];
}

__global__ void scan_pass2(int* __restrict__ bsum, int nb) {
  __shared__ int sh[256];
  int tid = threadIdx.x;
  int v = (tid < nb) ? bsum[tid] : 0;
  sh[tid] = v;
  __syncthreads();
  for (int off = 1; off < 256; off <<= 1) {
    int x = (tid >= off) ? sh[tid - off] : 0;
    __syncthreads();
    sh[tid] += x;
    __syncthreads();
  }
  if (tid < nb) bsum[tid] = sh[tid] - v;
}

__global__ void scan_pass3(int* __restrict__ rs, const int* __restrict__ bsum,
                           int* __restrict__ cursor, int N, int N1) {
  int i = blockIdx.x * 256 + threadIdx.x;
  if (i < N1) {
    int v = rs[i] + bsum[blockIdx.x];
    rs[i] = v;
    if (i < N) cursor[i] = v;
  }
}

__global__ void scatter_sorted(const int* __restrict__ ei, const int* __restrict__ et,
                               int E, int* __restrict__ cursor, int* __restrict__ sorted) {
  int i = blockIdx.x * blockDim.x + threadIdx.x;
  int stride = gridDim.x * blockDim.x;
  for (int e = i; e < E; e += stride) {
    int d = ei[E + e];
    int pos = atomicAdd(&cursor[d], 1);
    sorted[pos] = ei[e] | (et[e] << 24);
  }
}

// =====================================================================
// PATH A: bf16 MFMA  (Xbig [N][1152] bf16, Wbig [128][1152] bf16)
// =====================================================================

// node_states f32 -> Xb[:, 0:128] bf16
__global__ void convert_x(const float* __restrict__ ns,
                          unsigned short* __restrict__ Xb, int N) {
  int i = blockIdx.x * blockDim.x + threadIdx.x;     // one thread per 8 floats
  int stride = gridDim.x * blockDim.x;
  int total = N * (HIDDEN / 8);
  for (; i < total; i += stride) {
    int row = i >> 4;
    int off = (i & 15) * 8;
    const float4* p = (const float4*)(ns + (size_t)row * HIDDEN + off);
    float4 a = p[0], b = p[1];
    ushort4 h0, h1;
    h0.x = f32_to_bf16(a.x); h0.y = f32_to_bf16(a.y);
    h0.z = f32_to_bf16(a.z); h0.w = f32_to_bf16(a.w);
    h1.x = f32_to_bf16(b.x); h1.y = f32_to_bf16(b.y);
    h1.z = f32_to_bf16(b.z); h1.w = f32_to_bf16(b.w);
    unsigned short* q = Xb + (size_t)row * KBIG + off;
    *(ushort4*)q = h0;
    *(ushort4*)(q + 4) = h1;
  }
}

// Wbig [128][1152] bf16 = [W_self | W_rel] rows
__global__ void convert_w(const float* __restrict__ Ws, const float* __restrict__ Wr,
                          unsigned short* __restrict__ Wb) {
  int i = blockIdx.x * blockDim.x + threadIdx.x;     // one thread per 8 elems
  int total = HIDDEN * (KBIG / 8);
  int stride = gridDim.x * blockDim.x;
  for (; i < total; i += stride) {
    int col = i / (KBIG / 8);
    int k = (i % (KBIG / 8)) * 8;
    const float* src;
    if (k < HIDDEN) src = Ws + (size_t)col * HIDDEN + k;
    else {
      int r = (k - HIDDEN) >> 7;
      int kk = (k - HIDDEN) & 127;
      src = Wr + (size_t)r * HIDDEN * HIDDEN + (size_t)col * HIDDEN + kk;
    }
    float4 a = *(const float4*)src, b = *(const float4*)(src + 4);
    ushort4 h0, h1;
    h0.x = f32_to_bf16(a.x); h0.y = f32_to_bf16(a.y);
    h0.z = f32_to_bf16(a.z); h0.w = f32_to_bf16(a.w);
    h1.x = f32_to_bf16(b.x); h1.y = f32_to_bf16(b.y);
    h1.z = f32_to_bf16(b.z); h1.w = f32_to_bf16(b.w);
    unsigned short* q = Wb + (size_t)col * KBIG + k;
    *(ushort4*)q = h0;
    *(ushort4*)(q + 4) = h1;
  }
}

// one wave per node: mean per-relation sums (f32 reads, f32 accum) -> bf16 Xb[:,128:]
__global__ __launch_bounds__(256) void gather_T(
    const float* __restrict__ ns, const int* __restrict__ sorted,
    const int* __restrict__ rs, unsigned short* __restrict__ Xb, int N)
{
  int wid = (int)((blockIdx.x * (unsigned)blockDim.x + threadIdx.x) >> 6);
  int lane = threadIdx.x & 63;
  if (wid >= N) return;
  int s0 = rs[wid], s1 = rs[wid + 1];

  float accx[N_REL], accy[N_REL];
  #pragma unroll
  for (int r = 0; r < N_REL; ++r) { accx[r] = 0.f; accy[r] = 0.f; }

  for (int eb = s0; eb < s1; eb += 64) {
    int m = min(64, s1 - eb);
    int pk = (lane < m) ? sorted[eb + lane] : 0;
    for (int j = 0; j < m; ++j) {
      int pkj = __shfl(pk, j);
      int src = pkj & 0x00FFFFFF;
      if (src >= N) src = 0;                      // defensive clamp
      int r = (pkj >> 24) & 7;
      float2 x = *(const float2*)(ns + (size_t)src * HIDDEN + lane * 2);
      #pragma unroll
      for (int rr = 0; rr < N_REL; ++rr)
        if (r == rr) { accx[rr] += x.x; accy[rr] += x.y; }
    }
  }

  float inv = (s1 > s0) ? 1.0f / (float)(s1 - s0) : 0.0f;
  unsigned short* Tp = Xb + (size_t)wid * KBIG + HIDDEN;
  #pragma unroll
  for (int r = 0; r < N_REL; ++r) {
    ushort2 o;
    o.x = f32_to_bf16(accx[r] * inv);
    o.y = f32_to_bf16(accy[r] * inv);
    *(ushort2*)(Tp + r * HIDDEN + lane * 2) = o;
  }
}

// out = relu(Xbig @ Wbig^T + b); 4 waves/block, wave = 16 rows x 128 cols.
// A frag: lane holds X[rowbase+(lane&15)][(lane>>4)*8 + j]; B frag:
// lane holds W[ct*16+(lane&15)][(lane>>4)*8 + j]; C/D: col=lane&15,
// row=(lane>>4)*4+reg  [m89-verified layout].
__global__ __launch_bounds__(256) void mfma_out(
    const unsigned short* __restrict__ Xb, const unsigned short* __restrict__ Wb,
    const float* __restrict__ b, float* __restrict__ out, int N)
{
  int wave = threadIdx.x >> 6;
  int lane = threadIdx.x & 63;
  int rowbase = blockIdx.x * 64 + wave * 16;

  int arow = rowbase + (lane & 15);
  if (arow >= N) arow = N - 1;                 // clamp loads; stores guarded
  int kgrp = (lane >> 4) * 8;

  const unsigned short* Ap = Xb + (size_t)arow * KBIG + kgrp;
  const unsigned short* Bp = Wb + (size_t)(lane & 15) * KBIG + kgrp;

  f32x4 acc[8];
  #pragma unroll
  for (int ct = 0; ct < 8; ++ct) acc[ct] = (f32x4){0.f, 0.f, 0.f, 0.f};

  for (int ks = 0; ks < 36; ++ks) {
    short8 a = *(const short8*)(Ap + ks * 32);
    #pragma unroll
    for (int ct = 0; ct < 8; ++ct) {
      short8 bf = *(const short8*)(Bp + (size_t)ct * 16 * KBIG + ks * 32);
      acc[ct] = __builtin_amdgcn_mfma_f32_16x16x32_bf16(a, bf, acc[ct], 0, 0, 0);
    }
  }

  int colb = lane & 15;
  int rowd = rowbase + (lane >> 4) * 4;
  #pragma unroll
  for (int ct = 0; ct < 8; ++ct) {
    int c = ct * 16 + colb;
    float bc = b[c];
    #pragma unroll
    for (int r = 0; r < 4; ++r) {
      int rr = rowd + r;
      if (rr < N)
        out[(size_t)rr * HIDDEN + c] = fmaxf(acc[ct][r] + bc, 0.f);
    }
  }
}

// =====================================================================
// PATH B (f32, R2-passing): gather to T f32 + staged f32 GEMM
// =====================================================================

__global__ __launch_bounds__(256) void gather_T_f32(
    const float* __restrict__ ns, const int* __restrict__ sorted,
    const int* __restrict__ rs, float* __restrict__ T, int N)
{
  int wid = (int)((blockIdx.x * (unsigned)blockDim.x + threadIdx.x) >> 6);
  int lane = threadIdx.x & 63;
  if (wid >= N) return;
  int s0 = rs[wid], s1 = rs[wid + 1];

  float2 acc[N_REL];
  #pragma unroll
  for (int r = 0; r < N_REL; ++r) { acc[r].x = 0.f; acc[r].y = 0.f; }

  for (int eb = s0; eb < s1; eb += 64) {
    int m = min(64, s1 - eb);
    int pk = (lane < m) ? sorted[eb + lane] : 0;
    for (int j = 0; j < m; ++j) {
      int pkj = __shfl(pk, j);
      int src = pkj & 0x00FFFFFF;
      int r = (pkj >> 24) & 7;
      float2 x = *(const float2*)(ns + (size_t)src * HIDDEN + lane * 2);
      #pragma unroll
      for (int rr = 0; rr < N_REL; ++rr)
        if (r == rr) { acc[rr].x += x.x; acc[rr].y += x.y; }
    }
  }

  float inv = (s1 > s0) ? 1.0f / (float)(s1 - s0) : 0.0f;
  float2* Tp = (float2*)(T + (size_t)wid * (N_REL * HIDDEN));
  #pragma unroll
  for (int r = 0; r < N_REL; ++r) {
    float2 o; o.x = acc[r].x * inv; o.y = acc[r].y * inv;
    Tp[r * 64 + lane] = o;
  }
}

__global__ __launch_bounds__(256) void out_kernel_f32(
    const float* __restrict__ ns, const float* __restrict__ T,
    const float* __restrict__ Ws, const float* __restrict__ Wrel,
    const float* __restrict__ b, float* __restrict__ out, int N)
{
  __shared__ float Xs[64][HIDDEN];
  int t = threadIdx.x;
  int base = blockIdx.x * 64;
  int cnt = min(64, N - base);
  int jg = t & 31;
  int eg = t >> 5;

  float acc[8][4];
  #pragma unroll
  for (int e = 0; e < 8; ++e)
    #pragma unroll
    for (int u = 0; u < 4; ++u) acc[e][u] = 0.f;

  for (int c = 0; c < 9; ++c) {
    for (int q = t; q < cnt * 32; q += 256) {
      int e = q >> 5, k4 = q & 31;
      const float4* p = (c == 0)
          ? (const float4*)(ns + (size_t)(base + e) * HIDDEN)
          : (const float4*)(T + (size_t)(base + e) * (N_REL * HIDDEN) + (c - 1) * HIDDEN);
      ((float4*)Xs[e])[k4] = p[k4];
    }
    __syncthreads();

    const float* Wp = ((c == 0) ? Ws : (Wrel + (size_t)(c - 1) * HIDDEN * HIDDEN))
                      + (size_t)jg * 4 * HIDDEN;
    for (int kc = 0; kc < HIDDEN; kc += 8) {
      float4 wa[4], wb[4];
      #pragma unroll
      for (int u = 0; u < 4; ++u) {
        wa[u] = *(const float4*)(Wp + u * HIDDEN + kc);
        wb[u] = *(const float4*)(Wp + u * HIDDEN + kc + 4);
      }
      #pragma unroll
      for (int e = 0; e < 8; ++e) {
        float4 xa = ((const float4*)Xs[eg * 8 + e])[kc >> 2];
        float4 xb = ((const float4*)Xs[eg * 8 + e])[(kc >> 2) + 1];
        #pragma unroll
        for (int u = 0; u < 4; ++u)
          acc[e][u] += dot4f(xa, wa[u]) + dot4f(xb, wb[u]);
      }
    }
    __syncthreads();
  }

  float bj[4];
  *(float4*)bj = *(const float4*)(b + jg * 4);

  #pragma unroll
  for (int e = 0; e < 8; ++e) {
    int row = eg * 8 + e;
    if (row < cnt) {
      float4 o;
      o.x = fmaxf(acc[e][0] + bj[0], 0.f);
      o.y = fmaxf(acc[e][1] + bj[1], 0.f);
      o.z = fmaxf(acc[e][2] + bj[2], 0.f);
      o.w = fmaxf(acc[e][3] + bj[3], 0.f);
      *(float4*)(out + (size_t)(base + row) * HIDDEN + jg * 4) = o;
    }
  }
}

// =====================================================================

extern "C" void kernel_launch(void* const* d_in, const int* in_sizes, int n_in,
                              void* d_out, int out_size, void* d_ws, size_t ws_size,
                              hipStream_t stream) {
  const float* node_states = (const float*)d_in[0];
  const int*   edge_index  = (const int*)d_in[1];   // [2, E]
  const int*   edge_type   = (const int*)d_in[2];   // [E]
  const float* W_self      = (const float*)d_in[3];
  const float* b_self      = (const float*)d_in[4];
  const float* W_rel       = (const float*)d_in[5];
  float* out = (float*)d_out;

  const int E = in_sizes[2];
  const int N = in_sizes[0] / HIDDEN;
  const int N1 = N + 1;
  const int NB = (N1 + 255) / 256;

  const size_t ints_elems = (size_t)N + (size_t)N1 + (size_t)N + 256 + (size_t)E;

  // Path A workspace: Xb bf16 [N][KBIG] + Wb bf16 [128][KBIG] + ints
  const size_t xbig = (size_t)N * KBIG;
  const size_t wbig = (size_t)HIDDEN * KBIG;
  const size_t needA = (xbig + wbig) * 2 + ints_elems * 4 + 64;

  // Path B workspace: T f32 [N][8][128] + ints
  const size_t needB = ((size_t)N * N_REL * HIDDEN + ints_elems) * 4 + 64;

  if (ws_size >= needA && NB <= 256 && N <= (1 << 24)) {
    unsigned short* Xb = (unsigned short*)d_ws;
    unsigned short* Wb = Xb + xbig;
    int* deg    = (int*)(Wb + wbig);
    int* rs     = deg + N;
    int* cursor = rs + N1;
    int* bsum   = cursor + N;
    int* sorted = bsum + 256;

    zero_i<<<64, 256, 0, stream>>>(deg, N);
    hist_dst<<<1024, 256, 0, stream>>>(edge_index, E, deg);
    scan_pass1<<<NB, 256, 0, stream>>>(deg, N, N1, rs, bsum);
    scan_pass2<<<1, 256, 0, stream>>>(bsum, NB);
    scan_pass3<<<NB, 256, 0, stream>>>(rs, bsum, cursor, N, N1);
    scatter_sorted<<<1024, 256, 0, stream>>>(edge_index, edge_type, E, cursor, sorted);

    convert_x<<<1024, 256, 0, stream>>>(node_states, Xb, N);
    convert_w<<<72, 256, 0, stream>>>(W_self, W_rel, Wb);
    gather_T<<<(N + 3) / 4, 256, 0, stream>>>(node_states, sorted, rs, Xb, N);
    mfma_out<<<(N + 63) / 64, 256, 0, stream>>>(Xb, Wb, b_self, out, N);
  } else if (ws_size >= needB && NB <= 256 && N <= (1 << 24)) {
    float* T    = (float*)d_ws;
    int* deg    = (int*)(T + (size_t)N * N_REL * HIDDEN);
    int* rs     = deg + N;
    int* cursor = rs + N1;
    int* bsum   = cursor + N;
    int* sorted = bsum + 256;

    zero_i<<<64, 256, 0, stream>>>(deg, N);
    hist_dst<<<1024, 256, 0, stream>>>(edge_index, E, deg);
    scan_pass1<<<NB, 256, 0, stream>>>(deg, N, N1, rs, bsum);
    scan_pass2<<<1, 256, 0, stream>>>(bsum, NB);
    scan_pass3<<<NB, 256, 0, stream>>>(rs, bsum, cursor, N, N1);
    scatter_sorted<<<1024, 256, 0, stream>>>(edge_index, edge_type, E, cursor, sorted);

    gather_T_f32<<<(N + 3) / 4, 256, 0, stream>>>(node_states, sorted, rs, T, N);
    out_kernel_f32<<<(N + 63) / 64, 256, 0, stream>>>(node_states, T, W_self, W_rel,
                                                      b_self, out, N);
  }
}

// Round 6
// 207.688 us; speedup vs baseline: 8.5127x; 1.3174x over previous
//
#include <hip/hip_runtime.h>

#define HIDDEN 128
#define N_REL 8
#define KBIG 1152   // (1 + N_REL) * HIDDEN

typedef short short8 __attribute__((ext_vector_type(8)));
typedef float f32x4 __attribute__((ext_vector_type(4)));

__device__ inline float dot4f(float4 a, float4 b) {
  return a.x*b.x + a.y*b.y + a.z*b.z + a.w*b.w;
}

__device__ inline unsigned short f32_to_bf16(float f) {
  unsigned u = __float_as_uint(f);
  unsigned r = (u + 0x7FFFu + ((u >> 16) & 1u)) >> 16;   // round-to-nearest-even
  return (unsigned short)r;
}

// ---------------- utilities ----------------
__global__ void zero_i(int* __restrict__ p, int n) {
  int i = blockIdx.x * blockDim.x + threadIdx.x;
  int stride = gridDim.x * blockDim.x;
  for (; i < n; i += stride) p[i] = 0;
}

// ---------------- shared preprocessing: counting-sort by dst ----------------
__global__ void hist_dst(const int* __restrict__ ei, int E, int* __restrict__ deg) {
  int i = blockIdx.x * blockDim.x + threadIdx.x;
  int stride = gridDim.x * blockDim.x;
  for (int e = i; e < E; e += stride) atomicAdd(&deg[ei[E + e]], 1);
}

__global__ void scan_pass1(const int* __restrict__ deg, int N, int N1,
                           int* __restrict__ rs, int* __restrict__ bsum) {
  __shared__ int sh[256];
  int tid = threadIdx.x;
  int i = blockIdx.x * 256 + tid;
  int v = (i < N) ? deg[i] : 0;
  sh[tid] = v;
  __syncthreads();
  for (int off = 1; off < 256; off <<= 1) {
    int x = (tid >= off) ? sh[tid - off] : 0;
    __syncthreads();
    sh[tid] += x;
    __syncthreads();
  }
  if (i < N1) rs[i] = sh[tid] - v;
  if (tid == 255) bsum[blockIdx.x] = sh[255];
}

__global__ void scan_pass2(int* __restrict__ bsum, int nb) {
  __shared__ int sh[256];
  int tid = threadIdx.x;
  int v = (tid < nb) ? bsum[tid] : 0;
  sh[tid] = v;
  __syncthreads();
  for (int off = 1; off < 256; off <<= 1) {
    int x = (tid >= off) ? sh[tid - off] : 0;
    __syncthreads();
    sh[tid] += x;
    __syncthreads();
  }
  if (tid < nb) bsum[tid] = sh[tid] - v;
}

__global__ void scan_pass3(int* __restrict__ rs, const int* __restrict__ bsum,
                           int* __restrict__ cursor, int N, int N1) {
  int i = blockIdx.x * 256 + threadIdx.x;
  if (i < N1) {
    int v = rs[i] + bsum[blockIdx.x];
    rs[i] = v;
    if (i < N) cursor[i] = v;
  }
}

__global__ void scatter_sorted(const int* __restrict__ ei, const int* __restrict__ et,
                               int E, int* __restrict__ cursor, int* __restrict__ sorted) {
  int i = blockIdx.x * blockDim.x + threadIdx.x;
  int stride = gridDim.x * blockDim.x;
  for (int e = i; e < E; e += stride) {
    int d = ei[E + e];
    int pos = atomicAdd(&cursor[d], 1);
    sorted[pos] = ei[e] | (et[e] << 24);
  }
}

// =====================================================================
// PATH A: bf16 MFMA  (Xbig [N][1152] bf16, Wbig [128][1152] bf16)
// =====================================================================

// Wbig [128][1152] bf16 = [W_self | W_rel] rows
__global__ void convert_w(const float* __restrict__ Ws, const float* __restrict__ Wr,
                          unsigned short* __restrict__ Wb) {
  int i = blockIdx.x * blockDim.x + threadIdx.x;     // one thread per 8 elems
  int total = HIDDEN * (KBIG / 8);
  int stride = gridDim.x * blockDim.x;
  for (; i < total; i += stride) {
    int col = i / (KBIG / 8);
    int k = (i % (KBIG / 8)) * 8;
    const float* src;
    if (k < HIDDEN) src = Ws + (size_t)col * HIDDEN + k;
    else {
      int r = (k - HIDDEN) >> 7;
      int kk = (k - HIDDEN) & 127;
      src = Wr + (size_t)r * HIDDEN * HIDDEN + (size_t)col * HIDDEN + kk;
    }
    float4 a = *(const float4*)src, b = *(const float4*)(src + 4);
    ushort4 h0, h1;
    h0.x = f32_to_bf16(a.x); h0.y = f32_to_bf16(a.y);
    h0.z = f32_to_bf16(a.z); h0.w = f32_to_bf16(a.w);
    h1.x = f32_to_bf16(b.x); h1.y = f32_to_bf16(b.y);
    h1.z = f32_to_bf16(b.z); h1.w = f32_to_bf16(b.w);
    unsigned short* q = Wb + (size_t)col * KBIG + k;
    *(ushort4*)q = h0;
    *(ushort4*)(q + 4) = h1;
  }
}

// one wave per node: mean per-relation sums (f32 reads, f32 accum) -> bf16
// Xb[:,128:1152]; also converts the node's own row into Xb[:,0:128].
__global__ __launch_bounds__(256) void gather_T(
    const float* __restrict__ ns, const int* __restrict__ sorted,
    const int* __restrict__ rs, unsigned short* __restrict__ Xb, int N)
{
  int wid = (int)((blockIdx.x * (unsigned)blockDim.x + threadIdx.x) >> 6);
  int lane = threadIdx.x & 63;
  if (wid >= N) return;
  int s0 = rs[wid], s1 = rs[wid + 1];

  float accx[N_REL], accy[N_REL];
  #pragma unroll
  for (int r = 0; r < N_REL; ++r) { accx[r] = 0.f; accy[r] = 0.f; }

  for (int eb = s0; eb < s1; eb += 64) {
    int m = min(64, s1 - eb);
    int pk = (lane < m) ? sorted[eb + lane] : 0;
    for (int j = 0; j < m; ++j) {
      int pkj = __shfl(pk, j);
      int src = pkj & 0x00FFFFFF;
      if (src >= N) src = 0;                      // defensive clamp
      int r = (pkj >> 24) & 7;
      float2 x = *(const float2*)(ns + (size_t)src * HIDDEN + lane * 2);
      #pragma unroll
      for (int rr = 0; rr < N_REL; ++rr)
        if (r == rr) { accx[rr] += x.x; accy[rr] += x.y; }
    }
  }

  float inv = (s1 > s0) ? 1.0f / (float)(s1 - s0) : 0.0f;
  unsigned short* Tp = Xb + (size_t)wid * KBIG + HIDDEN;
  #pragma unroll
  for (int r = 0; r < N_REL; ++r) {
    ushort2 o;
    o.x = f32_to_bf16(accx[r] * inv);
    o.y = f32_to_bf16(accy[r] * inv);
    *(ushort2*)(Tp + r * HIDDEN + lane * 2) = o;
  }

  // own-row f32 -> bf16 into Xb[:, 0:128] (fused old convert_x)
  float2 own = *(const float2*)(ns + (size_t)wid * HIDDEN + lane * 2);
  ushort2 oo;
  oo.x = f32_to_bf16(own.x);
  oo.y = f32_to_bf16(own.y);
  *(ushort2*)(Xb + (size_t)wid * KBIG + lane * 2) = oo;
}

// out = relu(Xbig @ Wbig^T + b)
// 128 rows/block, 4 waves; wave = 32 rows (2 row-groups) x 128 cols (8 col-tiles).
// Manual double-buffer: prefetch ks+1 fragments during ks MFMAs.
// A frag: lane holds X[row][(lane>>4)*8 + j]; B frag: W[ct*16+(lane&15)][...];
// C/D: col=lane&15, row=(lane>>4)*4+reg  [m89-verified layout].
__global__ __launch_bounds__(256) void mfma_out(
    const unsigned short* __restrict__ Xb, const unsigned short* __restrict__ Wb,
    const float* __restrict__ b, float* __restrict__ out, int N)
{
  int wave = threadIdx.x >> 6;
  int lane = threadIdx.x & 63;
  int colb = lane & 15;
  int kgrp = (lane >> 4) * 8;
  int rowbase = blockIdx.x * 128 + wave * 32;

  const unsigned short* Ap[2];
  #pragma unroll
  for (int rg = 0; rg < 2; ++rg) {
    int r = rowbase + rg * 16 + colb;
    if (r >= N) r = N - 1;                 // clamp loads; stores guarded
    Ap[rg] = Xb + (size_t)r * KBIG + kgrp;
  }
  const unsigned short* Bp = Wb + (size_t)colb * KBIG + kgrp;

  f32x4 acc[2][8];
  #pragma unroll
  for (int rg = 0; rg < 2; ++rg)
    #pragma unroll
    for (int ct = 0; ct < 8; ++ct) acc[rg][ct] = (f32x4){0.f, 0.f, 0.f, 0.f};

  short8 a[2], bb[8];
  #pragma unroll
  for (int rg = 0; rg < 2; ++rg) a[rg] = *(const short8*)(Ap[rg]);
  #pragma unroll
  for (int ct = 0; ct < 8; ++ct) bb[ct] = *(const short8*)(Bp + (size_t)ct * 16 * KBIG);

  for (int ks = 0; ks < 36; ++ks) {
    short8 an[2], bn[8];
    if (ks < 35) {
      int off = (ks + 1) * 32;
      #pragma unroll
      for (int rg = 0; rg < 2; ++rg) an[rg] = *(const short8*)(Ap[rg] + off);
      #pragma unroll
      for (int ct = 0; ct < 8; ++ct)
        bn[ct] = *(const short8*)(Bp + (size_t)ct * 16 * KBIG + off);
    }
    #pragma unroll
    for (int rg = 0; rg < 2; ++rg)
      #pragma unroll
      for (int ct = 0; ct < 8; ++ct)
        acc[rg][ct] = __builtin_amdgcn_mfma_f32_16x16x32_bf16(a[rg], bb[ct],
                                                              acc[rg][ct], 0, 0, 0);
    #pragma unroll
    for (int rg = 0; rg < 2; ++rg) a[rg] = an[rg];
    #pragma unroll
    for (int ct = 0; ct < 8; ++ct) bb[ct] = bn[ct];
  }

  float bc[8];
  #pragma unroll
  for (int ct = 0; ct < 8; ++ct) bc[ct] = b[ct * 16 + colb];

  #pragma unroll
  for (int rg = 0; rg < 2; ++rg) {
    int rowd = rowbase + rg * 16 + (lane >> 4) * 4;
    #pragma unroll
    for (int ct = 0; ct < 8; ++ct) {
      int c = ct * 16 + colb;
      #pragma unroll
      for (int r = 0; r < 4; ++r) {
        int rr = rowd + r;
        if (rr < N)
          out[(size_t)rr * HIDDEN + c] = fmaxf(acc[rg][ct][r] + bc[ct], 0.f);
      }
    }
  }
}

// =====================================================================
// PATH B (f32, R2-passing): gather to T f32 + staged f32 GEMM
// =====================================================================

__global__ __launch_bounds__(256) void gather_T_f32(
    const float* __restrict__ ns, const int* __restrict__ sorted,
    const int* __restrict__ rs, float* __restrict__ T, int N)
{
  int wid = (int)((blockIdx.x * (unsigned)blockDim.x + threadIdx.x) >> 6);
  int lane = threadIdx.x & 63;
  if (wid >= N) return;
  int s0 = rs[wid], s1 = rs[wid + 1];

  float2 acc[N_REL];
  #pragma unroll
  for (int r = 0; r < N_REL; ++r) { acc[r].x = 0.f; acc[r].y = 0.f; }

  for (int eb = s0; eb < s1; eb += 64) {
    int m = min(64, s1 - eb);
    int pk = (lane < m) ? sorted[eb + lane] : 0;
    for (int j = 0; j < m; ++j) {
      int pkj = __shfl(pk, j);
      int src = pkj & 0x00FFFFFF;
      int r = (pkj >> 24) & 7;
      float2 x = *(const float2*)(ns + (size_t)src * HIDDEN + lane * 2);
      #pragma unroll
      for (int rr = 0; rr < N_REL; ++rr)
        if (r == rr) { acc[rr].x += x.x; acc[rr].y += x.y; }
    }
  }

  float inv = (s1 > s0) ? 1.0f / (float)(s1 - s0) : 0.0f;
  float2* Tp = (float2*)(T + (size_t)wid * (N_REL * HIDDEN));
  #pragma unroll
  for (int r = 0; r < N_REL; ++r) {
    float2 o; o.x = acc[r].x * inv; o.y = acc[r].y * inv;
    Tp[r * 64 + lane] = o;
  }
}

__global__ __launch_bounds__(256) void out_kernel_f32(
    const float* __restrict__ ns, const float* __restrict__ T,
    const float* __restrict__ Ws, const float* __restrict__ Wrel,
    const float* __restrict__ b, float* __restrict__ out, int N)
{
  __shared__ float Xs[64][HIDDEN];
  int t = threadIdx.x;
  int base = blockIdx.x * 64;
  int cnt = min(64, N - base);
  int jg = t & 31;
  int eg = t >> 5;

  float acc[8][4];
  #pragma unroll
  for (int e = 0; e < 8; ++e)
    #pragma unroll
    for (int u = 0; u < 4; ++u) acc[e][u] = 0.f;

  for (int c = 0; c < 9; ++c) {
    for (int q = t; q < cnt * 32; q += 256) {
      int e = q >> 5, k4 = q & 31;
      const float4* p = (c == 0)
          ? (const float4*)(ns + (size_t)(base + e) * HIDDEN)
          : (const float4*)(T + (size_t)(base + e) * (N_REL * HIDDEN) + (c - 1) * HIDDEN);
      ((float4*)Xs[e])[k4] = p[k4];
    }
    __syncthreads();

    const float* Wp = ((c == 0) ? Ws : (Wrel + (size_t)(c - 1) * HIDDEN * HIDDEN))
                      + (size_t)jg * 4 * HIDDEN;
    for (int kc = 0; kc < HIDDEN; kc += 8) {
      float4 wa[4], wb[4];
      #pragma unroll
      for (int u = 0; u < 4; ++u) {
        wa[u] = *(const float4*)(Wp + u * HIDDEN + kc);
        wb[u] = *(const float4*)(Wp + u * HIDDEN + kc + 4);
      }
      #pragma unroll
      for (int e = 0; e < 8; ++e) {
        float4 xa = ((const float4*)Xs[eg * 8 + e])[kc >> 2];
        float4 xb = ((const float4*)Xs[eg * 8 + e])[(kc >> 2) + 1];
        #pragma unroll
        for (int u = 0; u < 4; ++u)
          acc[e][u] += dot4f(xa, wa[u]) + dot4f(xb, wb[u]);
      }
    }
    __syncthreads();
  }

  float bj[4];
  *(float4*)bj = *(const float4*)(b + jg * 4);

  #pragma unroll
  for (int e = 0; e < 8; ++e) {
    int row = eg * 8 + e;
    if (row < cnt) {
      float4 o;
      o.x = fmaxf(acc[e][0] + bj[0], 0.f);
      o.y = fmaxf(acc[e][1] + bj[1], 0.f);
      o.z = fmaxf(acc[e][2] + bj[2], 0.f);
      o.w = fmaxf(acc[e][3] + bj[3], 0.f);
      *(float4*)(out + (size_t)(base + row) * HIDDEN + jg * 4) = o;
    }
  }
}

// =====================================================================

extern "C" void kernel_launch(void* const* d_in, const int* in_sizes, int n_in,
                              void* d_out, int out_size, void* d_ws, size_t ws_size,
                              hipStream_t stream) {
  const float* node_states = (const float*)d_in[0];
  const int*   edge_index  = (const int*)d_in[1];   // [2, E]
  const int*   edge_type   = (const int*)d_in[2];   // [E]
  const float* W_self      = (const float*)d_in[3];
  const float* b_self      = (const float*)d_in[4];
  const float* W_rel       = (const float*)d_in[5];
  float* out = (float*)d_out;

  const int E = in_sizes[2];
  const int N = in_sizes[0] / HIDDEN;
  const int N1 = N + 1;
  const int NB = (N1 + 255) / 256;

  const size_t ints_elems = (size_t)N + (size_t)N1 + (size_t)N + 256 + (size_t)E;

  // Path A workspace: Xb bf16 [N][KBIG] + Wb bf16 [128][KBIG] + ints
  const size_t xbig = (size_t)N * KBIG;
  const size_t wbig = (size_t)HIDDEN * KBIG;
  const size_t needA = (xbig + wbig) * 2 + ints_elems * 4 + 64;

  // Path B workspace: T f32 [N][8][128] + ints
  const size_t needB = ((size_t)N * N_REL * HIDDEN + ints_elems) * 4 + 64;

  if (ws_size >= needA && NB <= 256 && N <= (1 << 24)) {
    unsigned short* Xb = (unsigned short*)d_ws;
    unsigned short* Wb = Xb + xbig;
    int* deg    = (int*)(Wb + wbig);
    int* rs     = deg + N;
    int* cursor = rs + N1;
    int* bsum   = cursor + N;
    int* sorted = bsum + 256;

    zero_i<<<64, 256, 0, stream>>>(deg, N);
    hist_dst<<<1024, 256, 0, stream>>>(edge_index, E, deg);
    scan_pass1<<<NB, 256, 0, stream>>>(deg, N, N1, rs, bsum);
    scan_pass2<<<1, 256, 0, stream>>>(bsum, NB);
    scan_pass3<<<NB, 256, 0, stream>>>(rs, bsum, cursor, N, N1);
    scatter_sorted<<<1024, 256, 0, stream>>>(edge_index, edge_type, E, cursor, sorted);

    convert_w<<<72, 256, 0, stream>>>(W_self, W_rel, Wb);
    gather_T<<<(N + 3) / 4, 256, 0, stream>>>(node_states, sorted, rs, Xb, N);
    mfma_out<<<(N + 127) / 128, 256, 0, stream>>>(Xb, Wb, b_self, out, N);
  } else if (ws_size >= needB && NB <= 256 && N <= (1 << 24)) {
    float* T    = (float*)d_ws;
    int* deg    = (int*)(T + (size_t)N * N_REL * HIDDEN);
    int* rs     = deg + N;
    int* cursor = rs + N1;
    int* bsum   = cursor + N;
    int* sorted = bsum + 256;

    zero_i<<<64, 256, 0, stream>>>(deg, N);
    hist_dst<<<1024, 256, 0, stream>>>(edge_index, E, deg);
    scan_pass1<<<NB, 256, 0, stream>>>(deg, N, N1, rs, bsum);
    scan_pass2<<<1, 256, 0, stream>>>(bsum, NB);
    scan_pass3<<<NB, 256, 0, stream>>>(rs, bsum, cursor, N, N1);
    scatter_sorted<<<1024, 256, 0, stream>>>(edge_index, edge_type, E, cursor, sorted);

    gather_T_f32<<<(N + 3) / 4, 256, 0, stream>>>(node_states, sorted, rs, T, N);
    out_kernel_f32<<<(N + 63) / 64, 256, 0, stream>>>(node_states, T, W_self, W_rel,
                                                      b_self, out, N);
  }
}

// Round 7
// 159.947 us; speedup vs baseline: 11.0536x; 1.2985x over previous
//
#include <hip/hip_runtime.h>

#define HIDDEN 128
#define N_REL 8
#define KBIG 1152   // (1 + N_REL) * HIDDEN
#define BK 32

typedef short short8 __attribute__((ext_vector_type(8)));
typedef float f32x4 __attribute__((ext_vector_type(4)));

__device__ inline float dot4f(float4 a, float4 b) {
  return a.x*b.x + a.y*b.y + a.z*b.z + a.w*b.w;
}

__device__ inline unsigned short f32_to_bf16(float f) {
  unsigned u = __float_as_uint(f);
  unsigned r = (u + 0x7FFFu + ((u >> 16) & 1u)) >> 16;   // round-to-nearest-even
  return (unsigned short)r;
}

__device__ inline void gload_lds16(const unsigned short* g, unsigned short* l) {
  __builtin_amdgcn_global_load_lds(
      (const __attribute__((address_space(1))) void*)g,
      (__attribute__((address_space(3))) void*)l, 16, 0, 0);
}

// ---------------- utilities ----------------
__global__ void zero_i(int* __restrict__ p, int n) {
  int i = blockIdx.x * blockDim.x + threadIdx.x;
  int stride = gridDim.x * blockDim.x;
  for (; i < n; i += stride) p[i] = 0;
}

// ---------------- shared preprocessing: counting-sort by dst ----------------
__global__ void hist_dst(const int* __restrict__ ei, int E, int* __restrict__ deg) {
  int i = blockIdx.x * blockDim.x + threadIdx.x;
  int stride = gridDim.x * blockDim.x;
  for (int e = i; e < E; e += stride) atomicAdd(&deg[ei[E + e]], 1);
}

__global__ void scan_pass1(const int* __restrict__ deg, int N, int N1,
                           int* __restrict__ rs, int* __restrict__ bsum) {
  __shared__ int sh[256];
  int tid = threadIdx.x;
  int i = blockIdx.x * 256 + tid;
  int v = (i < N) ? deg[i] : 0;
  sh[tid] = v;
  __syncthreads();
  for (int off = 1; off < 256; off <<= 1) {
    int x = (tid >= off) ? sh[tid - off] : 0;
    __syncthreads();
    sh[tid] += x;
    __syncthreads();
  }
  if (i < N1) rs[i] = sh[tid] - v;
  if (tid == 255) bsum[blockIdx.x] = sh[255];
}

__global__ void scan_pass2(int* __restrict__ bsum, int nb) {
  __shared__ int sh[256];
  int tid = threadIdx.x;
  int v = (tid < nb) ? bsum[tid] : 0;
  sh[tid] = v;
  __syncthreads();
  for (int off = 1; off < 256; off <<= 1) {
    int x = (tid >= off) ? sh[tid - off] : 0;
    __syncthreads();
    sh[tid] += x;
    __syncthreads();
  }
  if (tid < nb) bsum[tid] = sh[tid] - v;
}

__global__ void scan_pass3(int* __restrict__ rs, const int* __restrict__ bsum,
                           int* __restrict__ cursor, int N, int N1) {
  int i = blockIdx.x * 256 + threadIdx.x;
  if (i < N1) {
    int v = rs[i] + bsum[blockIdx.x];
    rs[i] = v;
    if (i < N) cursor[i] = v;
  }
}

__global__ void scatter_sorted(const int* __restrict__ ei, const int* __restrict__ et,
                               int E, int* __restrict__ cursor, int* __restrict__ sorted) {
  int i = blockIdx.x * blockDim.x + threadIdx.x;
  int stride = gridDim.x * blockDim.x;
  for (int e = i; e < E; e += stride) {
    int d = ei[E + e];
    int pos = atomicAdd(&cursor[d], 1);
    sorted[pos] = ei[e] | (et[e] << 24);
  }
}

// =====================================================================
// PATH A: bf16 MFMA  (Xbig [N][1152] bf16, Wbig [128][1152] bf16)
// =====================================================================

// Wbig [128][1152] bf16 = [W_self | W_rel] rows
__global__ void convert_w(const float* __restrict__ Ws, const float* __restrict__ Wr,
                          unsigned short* __restrict__ Wb) {
  int i = blockIdx.x * blockDim.x + threadIdx.x;     // one thread per 8 elems
  int total = HIDDEN * (KBIG / 8);
  int stride = gridDim.x * blockDim.x;
  for (; i < total; i += stride) {
    int col = i / (KBIG / 8);
    int k = (i % (KBIG / 8)) * 8;
    const float* src;
    if (k < HIDDEN) src = Ws + (size_t)col * HIDDEN + k;
    else {
      int r = (k - HIDDEN) >> 7;
      int kk = (k - HIDDEN) & 127;
      src = Wr + (size_t)r * HIDDEN * HIDDEN + (size_t)col * HIDDEN + kk;
    }
    float4 a = *(const float4*)src, b = *(const float4*)(src + 4);
    ushort4 h0, h1;
    h0.x = f32_to_bf16(a.x); h0.y = f32_to_bf16(a.y);
    h0.z = f32_to_bf16(a.z); h0.w = f32_to_bf16(a.w);
    h1.x = f32_to_bf16(b.x); h1.y = f32_to_bf16(b.y);
    h1.z = f32_to_bf16(b.z); h1.w = f32_to_bf16(b.w);
    unsigned short* q = Wb + (size_t)col * KBIG + k;
    *(ushort4*)q = h0;
    *(ushort4*)(q + 4) = h1;
  }
}

// one wave per node: mean per-relation sums (f32 reads, f32 accum) -> bf16
// Xb[:,128:1152]; also converts the node's own row into Xb[:,0:128].
__global__ __launch_bounds__(256) void gather_T(
    const float* __restrict__ ns, const int* __restrict__ sorted,
    const int* __restrict__ rs, unsigned short* __restrict__ Xb, int N)
{
  int wid = (int)((blockIdx.x * (unsigned)blockDim.x + threadIdx.x) >> 6);
  int lane = threadIdx.x & 63;
  if (wid >= N) return;
  int s0 = rs[wid], s1 = rs[wid + 1];

  float accx[N_REL], accy[N_REL];
  #pragma unroll
  for (int r = 0; r < N_REL; ++r) { accx[r] = 0.f; accy[r] = 0.f; }

  for (int eb = s0; eb < s1; eb += 64) {
    int m = min(64, s1 - eb);
    int pk = (lane < m) ? sorted[eb + lane] : 0;
    for (int j = 0; j < m; ++j) {
      int pkj = __shfl(pk, j);
      int src = pkj & 0x00FFFFFF;
      if (src >= N) src = 0;                      // defensive clamp
      int r = (pkj >> 24) & 7;
      float2 x = *(const float2*)(ns + (size_t)src * HIDDEN + lane * 2);
      #pragma unroll
      for (int rr = 0; rr < N_REL; ++rr)
        if (r == rr) { accx[rr] += x.x; accy[rr] += x.y; }
    }
  }

  float inv = (s1 > s0) ? 1.0f / (float)(s1 - s0) : 0.0f;
  unsigned short* Tp = Xb + (size_t)wid * KBIG + HIDDEN;
  #pragma unroll
  for (int r = 0; r < N_REL; ++r) {
    ushort2 o;
    o.x = f32_to_bf16(accx[r] * inv);
    o.y = f32_to_bf16(accy[r] * inv);
    *(ushort2*)(Tp + r * HIDDEN + lane * 2) = o;
  }

  // own-row f32 -> bf16 into Xb[:, 0:128] (fused old convert_x)
  float2 own = *(const float2*)(ns + (size_t)wid * HIDDEN + lane * 2);
  ushort2 oo;
  oo.x = f32_to_bf16(own.x);
  oo.y = f32_to_bf16(own.y);
  *(ushort2*)(Xb + (size_t)wid * KBIG + lane * 2) = oo;
}

// out = relu(Xbig @ Wbig^T + b)  — m97-style LDS double-buffered MFMA GEMM.
// 128 rows x 128 cols per block, BK=32, 4 waves; wave = 64x64 (acc 4x4).
// Staging: global_load_lds width 16 (2 issues A + 2 issues B per K-step).
// A/B frag: lane holds row/col = base+(lane&15), k = (lane>>4)*8  [R5/R6-validated];
// C/D: col=lane&15, row=(lane>>4)*4+reg  [m89, R5/R6-validated].
__global__ __launch_bounds__(256) void mfma_out(
    const unsigned short* __restrict__ Xb, const unsigned short* __restrict__ Wb,
    const float* __restrict__ b, float* __restrict__ out, int N)
{
  __shared__ unsigned short As[2][128][BK];   // 8 KB each buf
  __shared__ unsigned short Bs[2][128][BK];

  int t = threadIdx.x;
  int lane = t & 63;
  int wave = t >> 6;
  int colb = lane & 15;
  int kq = (lane >> 4) * 8;
  int wr = (wave >> 1) * 64;          // wave row offset in tile
  int wc = (wave & 1) * 64;           // wave col offset in tile
  int rowbase = blockIdx.x * 128;

  // staging indices (thread t, issue i): t' = i*256+t; row=t'>>2; k8=(t'&3)*8
  int srow0 = t >> 2,          sk0 = (t & 3) * 8;
  int srow1 = (256 + t) >> 2,  sk1 = sk0;       // (t'&3) same for +256

  int ga0 = rowbase + srow0; if (ga0 >= N) ga0 = N - 1;
  int ga1 = rowbase + srow1; if (ga1 >= N) ga1 = N - 1;

  f32x4 acc[4][4];
  #pragma unroll
  for (int m = 0; m < 4; ++m)
    #pragma unroll
    for (int n = 0; n < 4; ++n) acc[m][n] = (f32x4){0.f, 0.f, 0.f, 0.f};

  // prologue: stage k0=0 into buf 0
  gload_lds16(Xb + (size_t)ga0 * KBIG + sk0, &As[0][srow0][sk0]);
  gload_lds16(Xb + (size_t)ga1 * KBIG + sk1, &As[0][srow1][sk1]);
  gload_lds16(Wb + (size_t)srow0 * KBIG + sk0, &Bs[0][srow0][sk0]);
  gload_lds16(Wb + (size_t)srow1 * KBIG + sk1, &Bs[0][srow1][sk1]);
  __syncthreads();

  int cur = 0;
  for (int ks = 0; ks < 36; ++ks) {
    if (ks < 35) {
      int k0 = (ks + 1) * BK;
      gload_lds16(Xb + (size_t)ga0 * KBIG + k0 + sk0, &As[cur ^ 1][srow0][sk0]);
      gload_lds16(Xb + (size_t)ga1 * KBIG + k0 + sk1, &As[cur ^ 1][srow1][sk1]);
      gload_lds16(Wb + (size_t)srow0 * KBIG + k0 + sk0, &Bs[cur ^ 1][srow0][sk0]);
      gload_lds16(Wb + (size_t)srow1 * KBIG + k0 + sk1, &Bs[cur ^ 1][srow1][sk1]);
    }

    short8 a[4], bb[4];
    #pragma unroll
    for (int m = 0; m < 4; ++m)
      a[m] = *(const short8*)&As[cur][wr + m * 16 + colb][kq];
    #pragma unroll
    for (int n = 0; n < 4; ++n)
      bb[n] = *(const short8*)&Bs[cur][wc + n * 16 + colb][kq];

    #pragma unroll
    for (int m = 0; m < 4; ++m)
      #pragma unroll
      for (int n = 0; n < 4; ++n)
        acc[m][n] = __builtin_amdgcn_mfma_f32_16x16x32_bf16(a[m], bb[n],
                                                            acc[m][n], 0, 0, 0);
    if (ks < 35) {
      __syncthreads();
      cur ^= 1;
    }
  }

  float bc[4];
  #pragma unroll
  for (int n = 0; n < 4; ++n) bc[n] = b[wc + n * 16 + colb];

  #pragma unroll
  for (int m = 0; m < 4; ++m) {
    int rowd = rowbase + wr + m * 16 + (lane >> 4) * 4;
    #pragma unroll
    for (int n = 0; n < 4; ++n) {
      int c = wc + n * 16 + colb;
      #pragma unroll
      for (int r = 0; r < 4; ++r) {
        int rr = rowd + r;
        if (rr < N)
          out[(size_t)rr * HIDDEN + c] = fmaxf(acc[m][n][r] + bc[n], 0.f);
      }
    }
  }
}

// =====================================================================
// PATH B (f32, R2-passing): gather to T f32 + staged f32 GEMM
// =====================================================================

__global__ __launch_bounds__(256) void gather_T_f32(
    const float* __restrict__ ns, const int* __restrict__ sorted,
    const int* __restrict__ rs, float* __restrict__ T, int N)
{
  int wid = (int)((blockIdx.x * (unsigned)blockDim.x + threadIdx.x) >> 6);
  int lane = threadIdx.x & 63;
  if (wid >= N) return;
  int s0 = rs[wid], s1 = rs[wid + 1];

  float2 acc[N_REL];
  #pragma unroll
  for (int r = 0; r < N_REL; ++r) { acc[r].x = 0.f; acc[r].y = 0.f; }

  for (int eb = s0; eb < s1; eb += 64) {
    int m = min(64, s1 - eb);
    int pk = (lane < m) ? sorted[eb + lane] : 0;
    for (int j = 0; j < m; ++j) {
      int pkj = __shfl(pk, j);
      int src = pkj & 0x00FFFFFF;
      int r = (pkj >> 24) & 7;
      float2 x = *(const float2*)(ns + (size_t)src * HIDDEN + lane * 2);
      #pragma unroll
      for (int rr = 0; rr < N_REL; ++rr)
        if (r == rr) { acc[rr].x += x.x; acc[rr].y += x.y; }
    }
  }

  float inv = (s1 > s0) ? 1.0f / (float)(s1 - s0) : 0.0f;
  float2* Tp = (float2*)(T + (size_t)wid * (N_REL * HIDDEN));
  #pragma unroll
  for (int r = 0; r < N_REL; ++r) {
    float2 o; o.x = acc[r].x * inv; o.y = acc[r].y * inv;
    Tp[r * 64 + lane] = o;
  }
}

__global__ __launch_bounds__(256) void out_kernel_f32(
    const float* __restrict__ ns, const float* __restrict__ T,
    const float* __restrict__ Ws, const float* __restrict__ Wrel,
    const float* __restrict__ b, float* __restrict__ out, int N)
{
  __shared__ float Xs[64][HIDDEN];
  int t = threadIdx.x;
  int base = blockIdx.x * 64;
  int cnt = min(64, N - base);
  int jg = t & 31;
  int eg = t >> 5;

  float acc[8][4];
  #pragma unroll
  for (int e = 0; e < 8; ++e)
    #pragma unroll
    for (int u = 0; u < 4; ++u) acc[e][u] = 0.f;

  for (int c = 0; c < 9; ++c) {
    for (int q = t; q < cnt * 32; q += 256) {
      int e = q >> 5, k4 = q & 31;
      const float4* p = (c == 0)
          ? (const float4*)(ns + (size_t)(base + e) * HIDDEN)
          : (const float4*)(T + (size_t)(base + e) * (N_REL * HIDDEN) + (c - 1) * HIDDEN);
      ((float4*)Xs[e])[k4] = p[k4];
    }
    __syncthreads();

    const float* Wp = ((c == 0) ? Ws : (Wrel + (size_t)(c - 1) * HIDDEN * HIDDEN))
                      + (size_t)jg * 4 * HIDDEN;
    for (int kc = 0; kc < HIDDEN; kc += 8) {
      float4 wa[4], wb[4];
      #pragma unroll
      for (int u = 0; u < 4; ++u) {
        wa[u] = *(const float4*)(Wp + u * HIDDEN + kc);
        wb[u] = *(const float4*)(Wp + u * HIDDEN + kc + 4);
      }
      #pragma unroll
      for (int e = 0; e < 8; ++e) {
        float4 xa = ((const float4*)Xs[eg * 8 + e])[kc >> 2];
        float4 xb = ((const float4*)Xs[eg * 8 + e])[(kc >> 2) + 1];
        #pragma unroll
        for (int u = 0; u < 4; ++u)
          acc[e][u] += dot4f(xa, wa[u]) + dot4f(xb, wb[u]);
      }
    }
    __syncthreads();
  }

  float bj[4];
  *(float4*)bj = *(const float4*)(b + jg * 4);

  #pragma unroll
  for (int e = 0; e < 8; ++e) {
    int row = eg * 8 + e;
    if (row < cnt) {
      float4 o;
      o.x = fmaxf(acc[e][0] + bj[0], 0.f);
      o.y = fmaxf(acc[e][1] + bj[1], 0.f);
      o.z = fmaxf(acc[e][2] + bj[2], 0.f);
      o.w = fmaxf(acc[e][3] + bj[3], 0.f);
      *(float4*)(out + (size_t)(base + row) * HIDDEN + jg * 4) = o;
    }
  }
}

// =====================================================================

extern "C" void kernel_launch(void* const* d_in, const int* in_sizes, int n_in,
                              void* d_out, int out_size, void* d_ws, size_t ws_size,
                              hipStream_t stream) {
  const float* node_states = (const float*)d_in[0];
  const int*   edge_index  = (const int*)d_in[1];   // [2, E]
  const int*   edge_type   = (const int*)d_in[2];   // [E]
  const float* W_self      = (const float*)d_in[3];
  const float* b_self      = (const float*)d_in[4];
  const float* W_rel       = (const float*)d_in[5];
  float* out = (float*)d_out;

  const int E = in_sizes[2];
  const int N = in_sizes[0] / HIDDEN;
  const int N1 = N + 1;
  const int NB = (N1 + 255) / 256;

  const size_t ints_elems = (size_t)N + (size_t)N1 + (size_t)N + 256 + (size_t)E;

  // Path A workspace: Xb bf16 [N][KBIG] + Wb bf16 [128][KBIG] + ints
  const size_t xbig = (size_t)N * KBIG;
  const size_t wbig = (size_t)HIDDEN * KBIG;
  const size_t needA = (xbig + wbig) * 2 + ints_elems * 4 + 64;

  // Path B workspace: T f32 [N][8][128] + ints
  const size_t needB = ((size_t)N * N_REL * HIDDEN + ints_elems) * 4 + 64;

  if (ws_size >= needA && NB <= 256 && N <= (1 << 24)) {
    unsigned short* Xb = (unsigned short*)d_ws;
    unsigned short* Wb = Xb + xbig;
    int* deg    = (int*)(Wb + wbig);
    int* rs     = deg + N;
    int* cursor = rs + N1;
    int* bsum   = cursor + N;
    int* sorted = bsum + 256;

    zero_i<<<64, 256, 0, stream>>>(deg, N);
    hist_dst<<<1024, 256, 0, stream>>>(edge_index, E, deg);
    scan_pass1<<<NB, 256, 0, stream>>>(deg, N, N1, rs, bsum);
    scan_pass2<<<1, 256, 0, stream>>>(bsum, NB);
    scan_pass3<<<NB, 256, 0, stream>>>(rs, bsum, cursor, N, N1);
    scatter_sorted<<<1024, 256, 0, stream>>>(edge_index, edge_type, E, cursor, sorted);

    convert_w<<<72, 256, 0, stream>>>(W_self, W_rel, Wb);
    gather_T<<<(N + 3) / 4, 256, 0, stream>>>(node_states, sorted, rs, Xb, N);
    mfma_out<<<(N + 127) / 128, 256, 0, stream>>>(Xb, Wb, b_self, out, N);
  } else if (ws_size >= needB && NB <= 256 && N <= (1 << 24)) {
    float* T    = (float*)d_ws;
    int* deg    = (int*)(T + (size_t)N * N_REL * HIDDEN);
    int* rs     = deg + N;
    int* cursor = rs + N1;
    int* bsum   = cursor + N;
    int* sorted = bsum + 256;

    zero_i<<<64, 256, 0, stream>>>(deg, N);
    hist_dst<<<1024, 256, 0, stream>>>(edge_index, E, deg);
    scan_pass1<<<NB, 256, 0, stream>>>(deg, N, N1, rs, bsum);
    scan_pass2<<<1, 256, 0, stream>>>(bsum, NB);
    scan_pass3<<<NB, 256, 0, stream>>>(rs, bsum, cursor, N, N1);
    scatter_sorted<<<1024, 256, 0, stream>>>(edge_index, edge_type, E, cursor, sorted);

    gather_T_f32<<<(N + 3) / 4, 256, 0, stream>>>(node_states, sorted, rs, T, N);
    out_kernel_f32<<<(N + 63) / 64, 256, 0, stream>>>(node_states, T, W_self, W_rel,
                                                      b_self, out, N);
  }
}